// Round 9
// baseline (274.271 us; speedup 1.0000x reference)
//
#include <hip/hip_runtime.h>

#define BB 2
#define SS 4096
#define EE 768
#define HH 12
#define DD 64
#define WW 256

typedef __attribute__((ext_vector_type(8))) short short8;
typedef __attribute__((ext_vector_type(4))) short short4v;
typedef __attribute__((ext_vector_type(4))) float floatx4;

#define MFMA16(a, b, c) __builtin_amdgcn_mfma_f32_16x16x32_bf16(a, b, c, 0, 0, 0)

__device__ __forceinline__ float bf2f(short x) {
    union { unsigned u; float f; } v;
    v.u = ((unsigned)(unsigned short)x) << 16;
    return v.f;
}

__device__ __forceinline__ short f2bf(float x) {
    union { float f; unsigned u; } v;
    v.f = x;
    unsigned r = v.u + 0x7fffu + ((v.u >> 16) & 1u);  // RNE
    return (short)(r >> 16);
}

__device__ __forceinline__ int imin(int a, int b) { return a < b ? a : b; }
__device__ __forceinline__ int imax(int a, int b) { return a > b ? a : b; }

// prep (R13/R14 version, passed): X fp32->bf16 blocks [0,6144) (1 float4/
// thread); W transpose blocks [6144,7872) (float4 loads, short4v stores).
// R16 taught: fusing X-conversion into the gemm moves the traffic onto the
// gemm's latency-bound critical path (61->73us) -- keep it streaming here.
__global__ __launch_bounds__(256) void prep(
    const float* __restrict__ hidden, const float* __restrict__ W0,
    const float* __restrict__ W1, const float* __restrict__ W2,
    short* __restrict__ Xb, short* __restrict__ Wt) {
    __shared__ short t[32][33];
    int bid = blockIdx.x;
    int tid = threadIdx.x;
    if (bid < 6144) {
        size_t i4 = (size_t)bid * 256 + tid;
        floatx4 f = *(const floatx4*)(hidden + i4 * 4);
        short4v s;
#pragma unroll
        for (int k = 0; k < 4; k++) s[k] = f2bf(f[k]);
        *(short4v*)(Xb + i4 * 4) = s;
    } else {
        int tmp = bid - 6144;
        int z = tmp / 576, r = tmp % 576;
        int bx = r % 24, by = r / 24;
        const float* in = (z == 0) ? W0 : (z == 1) ? W1 : W2;
        short* op = Wt + (size_t)z * EE * EE;
        int y0 = by * 32;
        int ty = tid >> 3, tx4 = tid & 7;
        floatx4 f = *(const floatx4*)&in[(size_t)(y0 + ty) * EE + bx * 32 + tx4 * 4];
#pragma unroll
        for (int k = 0; k < 4; k++) t[ty][tx4 * 4 + k] = f2bf(f[k]);
        __syncthreads();
        int A = tid >> 3, B0 = (tid & 7) * 4;
        short4v v;
#pragma unroll
        for (int k = 0; k < 4; k++) v[k] = t[B0 + k][A];
        *(short4v*)&op[(size_t)(bx * 32 + A) * EE + y0 + B0] = v;
    }
}

// C = Xb * W^T(+bias), Xb bf16:[8192][768], Wt bf16:[3][768(n)][768(k)]
// z=0: Q*(1/8) -> [B,H,S,D];  z=1: K -> [B,H,S,D];  z=2: V -> [B,H,D,S]
// R17: NO-LDS L2/L3-direct GEMM. Five LDS-staged structures (drain/pipeline/
// swizzle/occupancy/fusion) all pinned at 60-73us with ~4000cy per K-step vs
// ~500cy of work -> the barrier-synced staging structure itself is the
// invariant cost, and the data L2/L3-fits (W 3.5MB total; B-panel 196KB x 18
// = 3.5MB per XCD L2; Xb 12.6MB in L3) -- Common-mistake #7. This version:
// zero LDS, zero barriers; each wave reads A/B fragments direct from global
// (lanes pair into 16 x 64B sectors/inst), 24-step full unroll folds all 144
// loads into offset: immediates on 6 base addresses; compiler free-schedules
// (the no-barrier regime where hipcc pipelining is known-good). ~8 blocks/CU
// resident (no LDS limit), ~32 waves/CU for latency hiding.
__global__ __launch_bounds__(256) void qkv_gemm(
    const short* __restrict__ Xb, const short* __restrict__ Wt,
    const float* __restrict__ Bq, const float* __restrict__ Bk, const float* __restrict__ Bv,
    short* __restrict__ Qo, short* __restrict__ Ko, short* __restrict__ Vto) {
    int z = blockIdx.z;
    const short* Wz = Wt + (size_t)z * EE * EE;
    const float* bias = (z == 0) ? Bq : (z == 1) ? Bk : Bv;

    int tid = threadIdx.x;
    int m0 = blockIdx.x * 64, n0 = blockIdx.y * 128;
    int wave = tid >> 6, lane = tid & 63, lquad = lane >> 4, lrow = lane & 15;
    int wm = (wave & 1) * 32, wn = (wave >> 1) * 64;

    floatx4 acc[2][4] = {};

    // per-lane fragment base pointers (K-offset folds into imm offsets)
    const short* abase0 = &Xb[(size_t)(m0 + wm + 0 * 16 + lrow) * EE + lquad * 8];
    const short* abase1 = &Xb[(size_t)(m0 + wm + 1 * 16 + lrow) * EE + lquad * 8];
    const short* bbase0 = &Wz[(size_t)(n0 + wn + 0 * 16 + lrow) * EE + lquad * 8];
    const short* bbase1 = &Wz[(size_t)(n0 + wn + 1 * 16 + lrow) * EE + lquad * 8];
    const short* bbase2 = &Wz[(size_t)(n0 + wn + 2 * 16 + lrow) * EE + lquad * 8];
    const short* bbase3 = &Wz[(size_t)(n0 + wn + 3 * 16 + lrow) * EE + lquad * 8];

#pragma unroll
    for (int t = 0; t < 24; ++t) {
        int k0 = t * 32;
        short8 af0 = *(const short8*)(abase0 + k0);
        short8 af1 = *(const short8*)(abase1 + k0);
        short8 bf0 = *(const short8*)(bbase0 + k0);
        short8 bf1 = *(const short8*)(bbase1 + k0);
        short8 bf2 = *(const short8*)(bbase2 + k0);
        short8 bf3 = *(const short8*)(bbase3 + k0);
        acc[0][0] = MFMA16(af0, bf0, acc[0][0]);
        acc[0][1] = MFMA16(af0, bf1, acc[0][1]);
        acc[0][2] = MFMA16(af0, bf2, acc[0][2]);
        acc[0][3] = MFMA16(af0, bf3, acc[0][3]);
        acc[1][0] = MFMA16(af1, bf0, acc[1][0]);
        acc[1][1] = MFMA16(af1, bf1, acc[1][1]);
        acc[1][2] = MFMA16(af1, bf2, acc[1][2]);
        acc[1][3] = MFMA16(af1, bf3, acc[1][3]);
    }

    if (z == 2) {
        // V, stored transposed: Vt[b,h,d,s]
        for (int nt = 0; nt < 4; nt++) {
            int gn = n0 + wn + nt * 16 + lrow;
            float bv = bias[gn];
            int h = gn >> 6, d = gn & 63;
            for (int mt = 0; mt < 2; mt++) {
                int gm0 = m0 + wm + mt * 16 + lquad * 4;  // multiple of 4
                int b = gm0 >> 12, s = gm0 & (SS - 1);
                short4v pk;
                for (int r = 0; r < 4; r++) pk[r] = f2bf(acc[mt][nt][r] + bv);
                *(short4v*)&Vto[(((size_t)(b * HH + h)) * DD + d) * SS + s] = pk;
            }
        }
    } else {
        short* out = (z == 0) ? Qo : Ko;
        float scale = (z == 0) ? 0.125f : 1.0f;
        for (int nt = 0; nt < 4; nt++) {
            int gn = n0 + wn + nt * 16 + lrow;
            float bv = bias[gn];
            int h = gn >> 6, d = gn & 63;
            for (int mt = 0; mt < 2; mt++) {
                int gmb = m0 + wm + mt * 16 + lquad * 4;
                for (int r = 0; r < 4; r++) {
                    int gm = gmb + r;
                    int b = gm >> 12, s = gm & (SS - 1);
                    float v = (acc[mt][nt][r] + bv) * scale;
                    out[(((size_t)(b * HH + h)) * SS + s) * DD + d] = f2bf(v);
                }
            }
        }
    }
}

// Sliding-window attention v5 (unchanged, passed): 128 queries/block
// (4 waves x 32 queries), double-buffered K/V staging, wave-uniform interior
// fast path, S^T = K*Q^T trick, s_setprio around compute cluster.
// Q,K bf16 [B,H,S,D]; Vt bf16 [B,H,D,S]; out fp32 [B,S,E].
__global__ __launch_bounds__(256) void band_attn(
    const short* __restrict__ Q, const short* __restrict__ K,
    const short* __restrict__ Vt, float* __restrict__ out) {
    int hb = blockIdx.x;  // 0..23 -> same-head chunks land on the same XCD
    int h = hb % HH, b = hb / HH;
    int chunk = blockIdx.y;  // 0..31, 128 queries
    int tid = threadIdx.x;
    int wave = tid >> 6, lane = tid & 63, lquad = lane >> 4, lrow = lane & 15;
    int qbase = chunk * 128 + wave * 32;  // this wave's 32 queries

    const short* Qh = Q + ((size_t)(b * HH + h)) * SS * DD;
    const short* Kh = K + ((size_t)(b * HH + h)) * SS * DD;
    const short* Vh = Vt + ((size_t)(b * HH + h)) * DD * SS;

    __shared__ __align__(16) short Ks[2][64 * 72];  // [key][d], double-buffered
    __shared__ __align__(16) short Vs[2][64 * 72];  // [d][key], double-buffered
    __shared__ __align__(16) short Ps[4][16 * 72];  // per wave: [q][key]
    short* Pw = &Ps[wave][0];

    // Persistent Q B-fragments for 2 m-tiles: B[n=query=lrow][k=d=lquad*8+j]
    short8 qf[2][2];
#pragma unroll
    for (int m = 0; m < 2; m++)
#pragma unroll
        for (int hh = 0; hh < 2; hh++)
            qf[m][hh] = *(const short8*)&Qh[(size_t)(qbase + m * 16 + lrow) * DD + hh * 32 + lquad * 8];

    floatx4 o[2][4] = {};
    float ls[2] = {0.0f, 0.0f};

    int kwin = chunk * 128 - WW;  // block's key-window start (10 tiles of 64)
    int srow = tid >> 3;          // 0..31
    int scol = (tid & 7) * 8;     // 0..56
    int tlo = wave >> 1;          // wave active on tiles [tlo, tlo+9)

    short8 kreg[2], vreg[2];
    auto loadTile = [&](int t) {
        int ks0 = kwin + t * 64;
#pragma unroll
        for (int i = 0; i < 2; i++) {
            int r = srow + i * 32;
            int gk = imin(imax(ks0 + r, 0), SS - 1);
            kreg[i] = *(const short8*)&Kh[(size_t)gk * DD + scol];
            int gv = imin(imax(ks0 + scol, 0), SS - 8);
            vreg[i] = *(const short8*)&Vh[(size_t)r * SS + gv];
        }
    };
    auto storeTile = [&](int buf) {
#pragma unroll
        for (int i = 0; i < 2; i++) {
            int r = srow + i * 32;
            *(short8*)&Ks[buf][r * 72 + scol] = kreg[i];
            *(short8*)&Vs[buf][r * 72 + scol] = vreg[i];
        }
    };

    loadTile(0);
    storeTile(0);
    __syncthreads();

    for (int t = 0; t < 10; t++) {
        int buf = t & 1;
        if (t < 9) loadTile(t + 1);  // in flight during this tile's compute

        if ((unsigned)(t - tlo) < 9u) {  // this wave's 544-key window
            int ks0 = kwin + t * 64;
            short8 kf[4][2], vf[4][2];
#pragma unroll
            for (int kt = 0; kt < 4; kt++)
#pragma unroll
                for (int hh = 0; hh < 2; hh++)
                    kf[kt][hh] = *(short8*)&Ks[buf][(kt * 16 + lrow) * 72 + hh * 32 + lquad * 8];
#pragma unroll
            for (int nt = 0; nt < 4; nt++)
#pragma unroll
                for (int hh = 0; hh < 2; hh++)
                    vf[nt][hh] = *(short8*)&Vs[buf][(nt * 16 + lrow) * 72 + hh * 32 + lquad * 8];

            int d0 = ks0 - qbase;
            bool interior = (d0 >= -225) && (d0 <= 193) && (ks0 >= 0) && (ks0 <= SS - 64);

            __builtin_amdgcn_s_setprio(1);  // favor this wave's MFMA/softmax cluster (T5)
#pragma unroll
            for (int m = 0; m < 2; m++) {
                int q = qbase + m * 16 + lrow;  // this lane's query (S^T: col = lane&15)
                floatx4 s[4];
#pragma unroll
                for (int kt = 0; kt < 4; kt++) {
                    floatx4 zz = {};
                    s[kt] = MFMA16(kf[kt][0], qf[m][0], zz);
                    s[kt] = MFMA16(kf[kt][1], qf[m][1], s[kt]);
                }
                float lacc = 0.0f;
                if (interior) {
#pragma unroll
                    for (int kt = 0; kt < 4; kt++) {
                        short4v pk;
#pragma unroll
                        for (int r = 0; r < 4; r++) {
                            float p = __expf(s[kt][r]);
                            pk[r] = f2bf(p);
                            lacc += bf2f(pk[r]);
                        }
                        *(short4v*)&Pw[lrow * 72 + kt * 16 + lquad * 4] = pk;
                    }
                } else {
#pragma unroll
                    for (int kt = 0; kt < 4; kt++) {
                        short4v pk;
#pragma unroll
                        for (int r = 0; r < 4; r++) {
                            int key = ks0 + kt * 16 + lquad * 4 + r;
                            bool valid = ((unsigned)(key - q + WW) <= 2u * WW) && ((unsigned)key < SS);
                            float p = valid ? __expf(s[kt][r]) : 0.0f;
                            pk[r] = f2bf(p);
                            lacc += bf2f(pk[r]);
                        }
                        *(short4v*)&Pw[lrow * 72 + kt * 16 + lquad * 4] = pk;
                    }
                }
                ls[m] += lacc;
                asm volatile("" ::: "memory");  // order P write->read (same-wave DS is in-order)
                short8 ap0 = *(short8*)&Pw[lrow * 72 + lquad * 8];
                short8 ap1 = *(short8*)&Pw[lrow * 72 + 32 + lquad * 8];
#pragma unroll
                for (int nt = 0; nt < 4; nt++) {
                    o[m][nt] = MFMA16(ap0, vf[nt][0], o[m][nt]);
                    o[m][nt] = MFMA16(ap1, vf[nt][1], o[m][nt]);
                }
            }
            __builtin_amdgcn_s_setprio(0);
        }

        if (t < 9) storeTile(buf ^ 1);  // tile t+1 into the other buffer
        __syncthreads();
    }

    // ls[m]: per-lane partials over this lane's quad; reduce across quads
#pragma unroll
    for (int m = 0; m < 2; m++) {
        ls[m] += __shfl_xor(ls[m], 16, 64);
        ls[m] += __shfl_xor(ls[m], 32, 64);
        ls[m] = 1.0f / ls[m];  // lane L holds 1/ls for query (L&15)
    }

#pragma unroll
    for (int m = 0; m < 2; m++) {
#pragma unroll
        for (int r = 0; r < 4; r++) {
            float linv = __shfl(ls[m], lquad * 4 + r, 64);
            int s = qbase + m * 16 + lquad * 4 + r;
#pragma unroll
            for (int nt = 0; nt < 4; nt++)
                out[((size_t)b * SS + s) * EE + h * DD + nt * 16 + lrow] = o[m][nt][r] * linv;
        }
    }
}

extern "C" void kernel_launch(void* const* d_in, const int* in_sizes, int n_in,
                              void* d_out, int out_size, void* d_ws, size_t ws_size,
                              hipStream_t stream) {
    const float* hidden = (const float*)d_in[0];
    const float* Wq = (const float*)d_in[1];
    const float* bq = (const float*)d_in[2];
    const float* Wk = (const float*)d_in[3];
    const float* bk = (const float*)d_in[4];
    const float* Wv = (const float*)d_in[5];
    const float* bv = (const float*)d_in[6];
    float* out = (float*)d_out;

    short* ws = (short*)d_ws;
    const size_t WSZ = (size_t)EE * EE;            // 589824
    const size_t QSZ = (size_t)BB * HH * SS * DD;  // 6291456
    short* Wt = ws;              // 3 * WSZ  (bf16)
    short* Qb = Wt + 3 * WSZ;    // Q  [B,H,S,D] bf16
    short* Kb = Qb + QSZ;        // K  [B,H,S,D] bf16
    short* Vtb = Kb + QSZ;       // Vt [B,H,D,S] bf16
    // ws total: 3*WSZ + 3*QSZ shorts = 41.3 MB
    // Xb (bf16 X, 12.6 MB) lives in d_out (25 MB fp32) — consumed by qkv_gemm
    // before band_attn overwrites d_out at the end of the stream.
    short* Xb = (short*)d_out;

    prep<<<dim3(6144 + 3 * 576, 1, 1), 256, 0, stream>>>(hidden, Wq, Wk, Wv, Xb, Wt);

    qkv_gemm<<<dim3(128, 6, 3), 256, 0, stream>>>(Xb, Wt, bq, bk, bv, Qb, Kb, Vtb);

    band_attn<<<dim3(HH * BB, SS / 128, 1), 256, 0, stream>>>(Qb, Kb, Vtb, out);
}

// Round 11
// 173.276 us; speedup vs baseline: 1.5829x; 1.5829x over previous
//
#include <hip/hip_runtime.h>

#define BB 2
#define SS 4096
#define EE 768
#define HH 12
#define DD 64
#define WW 256

typedef __attribute__((ext_vector_type(8))) short short8;
typedef __attribute__((ext_vector_type(4))) short short4v;
typedef __attribute__((ext_vector_type(4))) float floatx4;

#define MFMA16(a, b, c) __builtin_amdgcn_mfma_f32_16x16x32_bf16(a, b, c, 0, 0, 0)

__device__ __forceinline__ float bf2f(short x) {
    union { unsigned u; float f; } v;
    v.u = ((unsigned)(unsigned short)x) << 16;
    return v.f;
}

__device__ __forceinline__ short f2bf(float x) {
    union { float f; unsigned u; } v;
    v.f = x;
    unsigned r = v.u + 0x7fffu + ((v.u >> 16) & 1u);  // RNE
    return (short)(r >> 16);
}

// R19 fix: __exp2f doesn't exist in HIP (R18 compile fail: glibc math.h macro
// collision). v_exp_f32 IS 2^x on gfx950 (ISA §3) -- inline asm wrapper.
__device__ __forceinline__ float exp2_fast(float x) {
    float r;
    asm("v_exp_f32 %0, %1" : "=v"(r) : "v"(x));
    return r;
}

__device__ __forceinline__ int imin(int a, int b) { return a < b ? a : b; }
__device__ __forceinline__ int imax(int a, int b) { return a > b ? a : b; }

// async global->LDS, 16B per lane; LDS dest must be wave-uniform-base + lane*16
__device__ __forceinline__ void gload_lds16(const short* g, short* l) {
    __builtin_amdgcn_global_load_lds(
        (const __attribute__((address_space(1))) unsigned*)g,
        (__attribute__((address_space(3))) unsigned*)l, 16, 0, 0);
}

// prep (R13 version, passed): X fp32->bf16 blocks [0,6144) (1 float4/thread);
// W transpose blocks [6144,7872) (float4 loads, short4v stores).
__global__ __launch_bounds__(256) void prep(
    const float* __restrict__ hidden, const float* __restrict__ W0,
    const float* __restrict__ W1, const float* __restrict__ W2,
    short* __restrict__ Xb, short* __restrict__ Wt) {
    __shared__ short t[32][33];
    int bid = blockIdx.x;
    int tid = threadIdx.x;
    if (bid < 6144) {
        size_t i4 = (size_t)bid * 256 + tid;
        floatx4 f = *(const floatx4*)(hidden + i4 * 4);
        short4v s;
#pragma unroll
        for (int k = 0; k < 4; k++) s[k] = f2bf(f[k]);
        *(short4v*)(Xb + i4 * 4) = s;
    } else {
        int tmp = bid - 6144;
        int z = tmp / 576, r = tmp % 576;
        int bx = r % 24, by = r / 24;
        const float* in = (z == 0) ? W0 : (z == 1) ? W1 : W2;
        short* op = Wt + (size_t)z * EE * EE;
        int y0 = by * 32;
        int ty = tid >> 3, tx4 = tid & 7;
        floatx4 f = *(const floatx4*)&in[(size_t)(y0 + ty) * EE + bx * 32 + tx4 * 4];
#pragma unroll
        for (int k = 0; k < 4; k++) t[ty][tx4 * 4 + k] = f2bf(f[k]);
        __syncthreads();
        int A = tid >> 3, B0 = (tid & 7) * 4;
        short4v v;
#pragma unroll
        for (int k = 0; k < 4; k++) v[k] = t[B0 + k][A];
        *(short4v*)&op[(size_t)(bx * 32 + A) * EE + y0 + B0] = v;
    }
}

// C = Xb * W^T(+bias), Xb bf16:[8192][768], Wt bf16:[3][768(n)][768(k)]
// z=0: Q*(log2e/8) -> [B,H,S,D] (exp2 softmax downstream);
// z=1: K -> [B,H,S,D];  z=2: V -> [B,H,D,S]
// R18/R19: COHORT reduction. Model fit to R0..R17: T_block ~16-19us invariant
// to structure (per-K-step latency floor ~1700cy); time = cohorts x T_block,
// cohorts = blocks/(256 x resident) (R12: 3.75x16.3=61 ✓; R15: 3.5x18.6=63 ✓).
// Only lever left: fewer, bigger blocks. 256x128 tile, 8 waves (512 thr),
// per-wave 64x64 acc[4][4] = exactly R12's proven shape; 576 blocks, LDS 72KB
// -> 2 blocks/CU -> cohorts ~1.5-2 -> predict 28-40us. Same swizzle bijection
// (A rows 0..255: chunk 512+tid has r=r0+128, same u), counted vmcnt(3)
// depth-2 pipeline, R12 epilogue with wm=(wave>>1)*64, wn=(wave&1)*64.
__global__ __launch_bounds__(512) void qkv_gemm(
    const short* __restrict__ Xb, const short* __restrict__ Wt,
    const float* __restrict__ Bq, const float* __restrict__ Bk, const float* __restrict__ Bv,
    short* __restrict__ Qo, short* __restrict__ Ko, short* __restrict__ Vto) {
    int z = blockIdx.z;
    const short* Wz = Wt + (size_t)z * EE * EE;
    const float* bias = (z == 0) ? Bq : (z == 1) ? Bk : Bv;

    __shared__ __align__(16) short As[3][256 * 32];  // 48 KB
    __shared__ __align__(16) short Bs[3][128 * 32];  // 24 KB
    int tid = threadIdx.x;
    int m0 = blockIdx.x * 256, n0 = blockIdx.y * 128;
    int wave = tid >> 6, lane = tid & 63, lquad = lane >> 4, lrow = lane & 15;
    int wm = (wave >> 1) * 64, wn = (wave & 1) * 64;

    floatx4 acc[4][4] = {};

    // staging chunks (16B each): A = 1024 chunks (rows 0..255): c0=tid,
    // c1=512+tid; B = 512 chunks (rows 0..127): cb=tid.
    // inverse of storage bijection c = (r>>1)*8 + ((q|((r&1)<<2)) ^ ((r>>1)&7)):
    int c0 = tid, c1 = 512 + tid;
    int u0 = (c0 & 7) ^ ((c0 >> 3) & 7);
    int r0s = (c0 >> 3) * 2 + (u0 >> 2), q0s = (u0 & 3) * 8;
    // c1: (512+tid)>>3 = 64+(tid>>3); &7 unchanged -> u1=u0, r1 = r0+128, q1=q0

    const short* xa0 = &Xb[(size_t)(m0 + r0s) * EE + q0s];
    const short* xa1 = xa0 + (size_t)128 * EE;
    const short* wb0 = &Wz[(size_t)(n0 + r0s) * EE + q0s];

    auto issueTile = [&](int t) {
        int k0 = t * 32;
        int bs = t % 3;
        gload_lds16(xa0 + k0, &As[bs][c0 * 8]);
        gload_lds16(xa1 + k0, &As[bs][c1 * 8]);
        gload_lds16(wb0 + k0, &Bs[bs][c0 * 8]);
    };

    // K-loop-invariant swizzled fragment-read offsets (shorts)
    int offA[4], offB[4];
#pragma unroll
    for (int mt = 0; mt < 4; mt++) {
        int ra = wm + mt * 16 + lrow;
        int sa = (lquad | ((ra & 1) << 2)) ^ ((ra >> 1) & 7);
        offA[mt] = (ra >> 1) * 64 + sa * 8;
        int rb = wn + mt * 16 + lrow;
        int sb = (lquad | ((rb & 1) << 2)) ^ ((rb >> 1) & 7);
        offB[mt] = (rb >> 1) * 64 + sb * 8;
    }

    issueTile(0);
    issueTile(1);

#pragma unroll
    for (int t = 0; t < 24; ++t) {
        // tile t's 3 loads done; tile t+1's 3 may stay in flight
        if (t < 23) asm volatile("s_waitcnt vmcnt(3)" ::: "memory");
        else        asm volatile("s_waitcnt vmcnt(0)" ::: "memory");
        __builtin_amdgcn_sched_barrier(0);  // pin prior ds_read/MFMA above the barrier
        __builtin_amdgcn_s_barrier();       // raw: no compiler vmcnt(0) drain
        asm volatile("" ::: "memory");

        if (t + 2 < 24) issueTile(t + 2);   // into buf[(t-1)%3], free since B_t

        int bs = t % 3;
        short8 af[4], bfv[4];
#pragma unroll
        for (int mt = 0; mt < 4; mt++)
            af[mt] = *(short8*)&As[bs][offA[mt]];
#pragma unroll
        for (int nt = 0; nt < 4; nt++)
            bfv[nt] = *(short8*)&Bs[bs][offB[nt]];
#pragma unroll
        for (int mt = 0; mt < 4; mt++)
#pragma unroll
            for (int nt = 0; nt < 4; nt++)
                acc[mt][nt] = MFMA16(af[mt], bfv[nt], acc[mt][nt]);
    }

    if (z == 2) {
        // V, stored transposed: Vt[b,h,d,s]
        for (int nt = 0; nt < 4; nt++) {
            int gn = n0 + wn + nt * 16 + lrow;
            float bv = bias[gn];
            int h = gn >> 6, d = gn & 63;
            for (int mt = 0; mt < 4; mt++) {
                int gm0 = m0 + wm + mt * 16 + lquad * 4;  // multiple of 4
                int b = gm0 >> 12, s = gm0 & (SS - 1);
                short4v pk;
                for (int r = 0; r < 4; r++) pk[r] = f2bf(acc[mt][nt][r] + bv);
                *(short4v*)&Vto[(((size_t)(b * HH + h)) * DD + d) * SS + s] = pk;
            }
        }
    } else {
        short* out = (z == 0) ? Qo : Ko;
        // Q carries 1/8 (head-dim scale) x log2(e) so attn can use exp2
        float scale = (z == 0) ? 0.125f * 1.44269504088896f : 1.0f;
        for (int nt = 0; nt < 4; nt++) {
            int gn = n0 + wn + nt * 16 + lrow;
            float bv = bias[gn];
            int h = gn >> 6, d = gn & 63;
            for (int mt = 0; mt < 4; mt++) {
                int gmb = m0 + wm + mt * 16 + lquad * 4;
                for (int r = 0; r < 4; r++) {
                    int gm = gmb + r;
                    int b = gm >> 12, s = gm & (SS - 1);
                    float v = (acc[mt][nt][r] + bv) * scale;
                    out[(((size_t)(b * HH + h)) * SS + s) * DD + d] = f2bf(v);
                }
            }
        }
    }
}

// Sliding-window attention v6: v5 + exp2 softmax (log2e folded into Q scale
// in the gemm; removes one v_mul per exp -> 288 VALU/wave off the softmax).
// 128 queries/block (4 waves x 32 queries), double-buffered K/V staging,
// wave-uniform interior fast path, S^T = K*Q^T trick, setprio on compute.
// Q,K bf16 [B,H,S,D]; Vt bf16 [B,H,D,S]; out fp32 [B,S,E].
__global__ __launch_bounds__(256) void band_attn(
    const short* __restrict__ Q, const short* __restrict__ K,
    const short* __restrict__ Vt, float* __restrict__ out) {
    int hb = blockIdx.x;  // 0..23 -> same-head chunks land on the same XCD
    int h = hb % HH, b = hb / HH;
    int chunk = blockIdx.y;  // 0..31, 128 queries
    int tid = threadIdx.x;
    int wave = tid >> 6, lane = tid & 63, lquad = lane >> 4, lrow = lane & 15;
    int qbase = chunk * 128 + wave * 32;  // this wave's 32 queries

    const short* Qh = Q + ((size_t)(b * HH + h)) * SS * DD;
    const short* Kh = K + ((size_t)(b * HH + h)) * SS * DD;
    const short* Vh = Vt + ((size_t)(b * HH + h)) * DD * SS;

    __shared__ __align__(16) short Ks[2][64 * 72];  // [key][d], double-buffered
    __shared__ __align__(16) short Vs[2][64 * 72];  // [d][key], double-buffered
    __shared__ __align__(16) short Ps[4][16 * 72];  // per wave: [q][key]
    short* Pw = &Ps[wave][0];

    // Persistent Q B-fragments for 2 m-tiles: B[n=query=lrow][k=d=lquad*8+j]
    short8 qf[2][2];
#pragma unroll
    for (int m = 0; m < 2; m++)
#pragma unroll
        for (int hh = 0; hh < 2; hh++)
            qf[m][hh] = *(const short8*)&Qh[(size_t)(qbase + m * 16 + lrow) * DD + hh * 32 + lquad * 8];

    floatx4 o[2][4] = {};
    float ls[2] = {0.0f, 0.0f};

    int kwin = chunk * 128 - WW;  // block's key-window start (10 tiles of 64)
    int srow = tid >> 3;          // 0..31
    int scol = (tid & 7) * 8;     // 0..56
    int tlo = wave >> 1;          // wave active on tiles [tlo, tlo+9)

    short8 kreg[2], vreg[2];
    auto loadTile = [&](int t) {
        int ks0 = kwin + t * 64;
#pragma unroll
        for (int i = 0; i < 2; i++) {
            int r = srow + i * 32;
            int gk = imin(imax(ks0 + r, 0), SS - 1);
            kreg[i] = *(const short8*)&Kh[(size_t)gk * DD + scol];
            int gv = imin(imax(ks0 + scol, 0), SS - 8);
            vreg[i] = *(const short8*)&Vh[(size_t)r * SS + gv];
        }
    };
    auto storeTile = [&](int buf) {
#pragma unroll
        for (int i = 0; i < 2; i++) {
            int r = srow + i * 32;
            *(short8*)&Ks[buf][r * 72 + scol] = kreg[i];
            *(short8*)&Vs[buf][r * 72 + scol] = vreg[i];
        }
    };

    loadTile(0);
    storeTile(0);
    __syncthreads();

    for (int t = 0; t < 10; t++) {
        int buf = t & 1;
        if (t < 9) loadTile(t + 1);  // in flight during this tile's compute

        if ((unsigned)(t - tlo) < 9u) {  // this wave's 544-key window
            int ks0 = kwin + t * 64;
            short8 kf[4][2], vf[4][2];
#pragma unroll
            for (int kt = 0; kt < 4; kt++)
#pragma unroll
                for (int hh = 0; hh < 2; hh++)
                    kf[kt][hh] = *(short8*)&Ks[buf][(kt * 16 + lrow) * 72 + hh * 32 + lquad * 8];
#pragma unroll
            for (int nt = 0; nt < 4; nt++)
#pragma unroll
                for (int hh = 0; hh < 2; hh++)
                    vf[nt][hh] = *(short8*)&Vs[buf][(nt * 16 + lrow) * 72 + hh * 32 + lquad * 8];

            int d0 = ks0 - qbase;
            bool interior = (d0 >= -225) && (d0 <= 193) && (ks0 >= 0) && (ks0 <= SS - 64);

            __builtin_amdgcn_s_setprio(1);  // favor this wave's MFMA/softmax cluster (T5)
#pragma unroll
            for (int m = 0; m < 2; m++) {
                int q = qbase + m * 16 + lrow;  // this lane's query (S^T: col = lane&15)
                floatx4 s[4];
#pragma unroll
                for (int kt = 0; kt < 4; kt++) {
                    floatx4 zz = {};
                    s[kt] = MFMA16(kf[kt][0], qf[m][0], zz);
                    s[kt] = MFMA16(kf[kt][1], qf[m][1], s[kt]);
                }
                float lacc = 0.0f;
                if (interior) {
#pragma unroll
                    for (int kt = 0; kt < 4; kt++) {
                        short4v pk;
#pragma unroll
                        for (int r = 0; r < 4; r++) {
                            float p = exp2_fast(s[kt][r]);  // log2e pre-folded into Q
                            pk[r] = f2bf(p);
                            lacc += bf2f(pk[r]);
                        }
                        *(short4v*)&Pw[lrow * 72 + kt * 16 + lquad * 4] = pk;
                    }
                } else {
#pragma unroll
                    for (int kt = 0; kt < 4; kt++) {
                        short4v pk;
#pragma unroll
                        for (int r = 0; r < 4; r++) {
                            int key = ks0 + kt * 16 + lquad * 4 + r;
                            bool valid = ((unsigned)(key - q + WW) <= 2u * WW) && ((unsigned)key < SS);
                            float p = valid ? exp2_fast(s[kt][r]) : 0.0f;
                            pk[r] = f2bf(p);
                            lacc += bf2f(pk[r]);
                        }
                        *(short4v*)&Pw[lrow * 72 + kt * 16 + lquad * 4] = pk;
                    }
                }
                ls[m] += lacc;
                asm volatile("" ::: "memory");  // order P write->read (same-wave DS is in-order)
                short8 ap0 = *(short8*)&Pw[lrow * 72 + lquad * 8];
                short8 ap1 = *(short8*)&Pw[lrow * 72 + 32 + lquad * 8];
#pragma unroll
                for (int nt = 0; nt < 4; nt++) {
                    o[m][nt] = MFMA16(ap0, vf[nt][0], o[m][nt]);
                    o[m][nt] = MFMA16(ap1, vf[nt][1], o[m][nt]);
                }
            }
            __builtin_amdgcn_s_setprio(0);
        }

        if (t < 9) storeTile(buf ^ 1);  // tile t+1 into the other buffer
        __syncthreads();
    }

    // ls[m]: per-lane partials over this lane's quad; reduce across quads
#pragma unroll
    for (int m = 0; m < 2; m++) {
        ls[m] += __shfl_xor(ls[m], 16, 64);
        ls[m] += __shfl_xor(ls[m], 32, 64);
        ls[m] = 1.0f / ls[m];  // lane L holds 1/ls for query (L&15)
    }

#pragma unroll
    for (int m = 0; m < 2; m++) {
#pragma unroll
        for (int r = 0; r < 4; r++) {
            float linv = __shfl(ls[m], lquad * 4 + r, 64);
            int s = qbase + m * 16 + lquad * 4 + r;
#pragma unroll
            for (int nt = 0; nt < 4; nt++)
                out[((size_t)b * SS + s) * EE + h * DD + nt * 16 + lrow] = o[m][nt][r] * linv;
        }
    }
}

extern "C" void kernel_launch(void* const* d_in, const int* in_sizes, int n_in,
                              void* d_out, int out_size, void* d_ws, size_t ws_size,
                              hipStream_t stream) {
    const float* hidden = (const float*)d_in[0];
    const float* Wq = (const float*)d_in[1];
    const float* bq = (const float*)d_in[2];
    const float* Wk = (const float*)d_in[3];
    const float* bk = (const float*)d_in[4];
    const float* Wv = (const float*)d_in[5];
    const float* bv = (const float*)d_in[6];
    float* out = (float*)d_out;

    short* ws = (short*)d_ws;
    const size_t WSZ = (size_t)EE * EE;            // 589824
    const size_t QSZ = (size_t)BB * HH * SS * DD;  // 6291456
    short* Wt = ws;              // 3 * WSZ  (bf16)
    short* Qb = Wt + 3 * WSZ;    // Q  [B,H,S,D] bf16
    short* Kb = Qb + QSZ;        // K  [B,H,S,D] bf16
    short* Vtb = Kb + QSZ;       // Vt [B,H,D,S] bf16
    // ws total: 3*WSZ + 3*QSZ shorts = 41.3 MB
    // Xb (bf16 X, 12.6 MB) lives in d_out (25 MB fp32) — consumed by qkv_gemm
    // before band_attn overwrites d_out at the end of the stream.
    short* Xb = (short*)d_out;

    prep<<<dim3(6144 + 3 * 576, 1, 1), 256, 0, stream>>>(hidden, Wq, Wk, Wv, Xb, Wt);

    qkv_gemm<<<dim3(32, 6, 3), 512, 0, stream>>>(Xb, Wt, bq, bk, bv, Qb, Kb, Vtb);

    band_attn<<<dim3(HH * BB, SS / 128, 1), 256, 0, stream>>>(Qb, Kb, Vtb, out);
}